// Round 23
// baseline (76.335 us; speedup 1.0000x reference)
//
#include <hip/hip_runtime.h>
#include <hip/hip_fp16.h>
#include <hip/hip_fp8.h>

#define MU_C     0.5f
#define C_NORM_C 8.0f
#define LRELU_C  0.2f
#define NCHEB    2   // output x_3; measured-kappa (~1.07) err ~6e-4 << 0.098

constexpr int BB = 16;   // batch
constexpr int KK = 16;   // neighbors
constexpr int EE = 6;    // embedding dim

typedef float v4f __attribute__((ext_vector_type(4)));

// ws scalar slots: sc[0] = norm accumulator (sum deg^2 + sum w^2)
//                  sc[2] = max_n deg_n (float bits via int atomicMax)

__device__ __forceinline__ void cheb_params(const float* __restrict__ sc,
                                            float& musc, float& theta, float& delta) {
    float scale = C_NORM_C * rsqrtf(sc[0] + 1e-30f);
    musc = MU_C * scale;
    float mdeg = __int_as_float(((const int*)sc)[2]) * scale;
    float lub = 1.f + MU_C * fminf(2.f * mdeg, 8.f);
    theta = 0.5f * (lub + 1.f);
    delta = fmaxf(0.5f * (lub - 1.f), 1e-12f);
}

// Features quantized to fp8 e4m3 (self-consistent pack/unpack; w
// perturbation stays under the bf16 output floor — measured r22).
// Row = 64B/node: byte = bq*16 + sub*4 + f  (b = bq*4+sub; f3 = pad).
// Also writes Bt = x^T f32 (N,16) and Bth = x^T f16 (N,16).
// Block 0 zeroes the scalar slots.
__global__ void k_feat(const float* __restrict__ x,
                       const float* __restrict__ emb,
                       const float* __restrict__ fcw,
                       const float* __restrict__ fcb,
                       unsigned char* __restrict__ ffp8,
                       float* __restrict__ Bt,
                       __half* __restrict__ Bth,
                       float* __restrict__ sc,
                       int N) {
    if (blockIdx.x == 0 && threadIdx.x < 64) sc[threadIdx.x] = 0.f;
    int n = blockIdx.x * blockDim.x + threadIdx.x;
    if (n >= N) return;
    float ev[EE];
#pragma unroll
    for (int j = 0; j < EE; ++j) ev[j] = emb[(size_t)n * EE + j];
    float g[3], w0[3];
#pragma unroll
    for (int f = 0; f < 3; ++f) {
        w0[f] = fcw[f * (EE + 1)];
        float s = fcb[f];
#pragma unroll
        for (int j = 0; j < EE; ++j) s += fcw[f * (EE + 1) + 1 + j] * ev[j];
        g[f] = s;
    }
    unsigned char hb8[64];
    float bt[BB];
    __half bth[BB];
#pragma unroll
    for (int b = 0; b < BB; ++b) {
        float xv = x[(size_t)b * N + n];
        bt[b] = xv;
        bth[b] = __float2half(xv);
        int bq = b >> 2, sub = b & 3;
        int base = bq * 16 + sub * 4;
#pragma unroll
        for (int f = 0; f < 3; ++f) {
            float v = g[f] + w0[f] * xv;
            v = (v >= 0.f) ? v : LRELU_C * v;
            __hip_fp8_e4m3 q(v);
            hb8[base + f] = (unsigned char)q.__x;
        }
        hb8[base + 3] = 0;
    }
    uint4* dst = (uint4*)(ffp8 + (size_t)n * 64);
#pragma unroll
    for (int q = 0; q < 4; ++q) dst[q] = ((const uint4*)hb8)[q];
    float4* db = (float4*)(Bt + (size_t)n * 16);
#pragma unroll
    for (int q = 0; q < 4; ++q) db[q] = ((const float4*)bt)[q];
    uint4* dh = (uint4*)(Bth + (size_t)n * 16);
#pragma unroll
    for (int q = 0; q < 2; ++q) dh[q] = ((const uint4*)bth)[q];
}

__device__ __forceinline__ void unpack_fp8_12(uint4 u, float* f) {
    const unsigned char* b = (const unsigned char*)&u;
#pragma unroll
    for (int sub = 0; sub < 4; ++sub) {
#pragma unroll
        for (int ff = 0; ff < 3; ++ff) {
            __hip_fp8_e4m3 h;
            h.__x = (__hip_fp8_storage_t)b[sub * 4 + ff];
            f[sub * 4 + ff] = (float)h;
        }
    }
}

// Similarity weights, 8 lanes/node split along the NEIGHBOR axis:
// lane = (khalf h, batch-quad bq). Each lane keeps its bq feature quad
// and gathers only 8 neighbors (serial chain halved; sum[8] live state
// LESS than the r21 form) -> 2x waves (24.4/CU) at equal/lower VGPR.
// Batch combine = 2-stage width-4 butterfly (bits 0-1); deg/F-norm get
// one extra xor-4 to merge khalves. wl written as float2 per lane.
__global__ void __launch_bounds__(256, 2)
k_weights(const int* __restrict__ nl,
          const unsigned char* __restrict__ ffp8,
          const float* __restrict__ theta_p,
          float* __restrict__ wl,
          float* __restrict__ sc,
          int N) {
    __shared__ float ldsS[8];
    __shared__ float ldsM[8];
    int t = blockIdx.x * blockDim.x + threadIdx.x;
    int n = t >> 3, lid = t & 7;
    int bq = lid & 3, h = lid >> 2;
    float tp = 0.f, dm = 0.f;
    if (n < N) {
        float inv2t = 0.5f / theta_p[0];
        const uint4* fu = (const uint4*)ffp8;     // 4 uint4 per node row
        uint4 su = fu[(size_t)n * 4 + bq];
        float fs[16];
        unpack_fp8_12(su, fs);
        int idx[8];
        const int4* ip = (const int4*)(nl + (size_t)n * KK + h * 8);
        ((int4*)idx)[0] = ip[0];
        ((int4*)idx)[1] = ip[1];
        float sum[8];
#pragma unroll
        for (int k = 0; k < 8; ++k) {
            int nbs = idx[k] < 0 ? 0 : idx[k];
            uint4 nu = fu[(size_t)nbs * 4 + bq];
            float fn[16];
            unpack_fp8_12(nu, fn);
            float s = 0.f;
#pragma unroll
            for (int b = 0; b < 4; ++b) {
                float d0 = fs[b * 4 + 0] - fn[b * 4 + 0];
                float d1 = fs[b * 4 + 1] - fn[b * 4 + 1];
                float d2 = fs[b * 4 + 2] - fn[b * 4 + 2];
                s += __expf(-(d0 * d0 + d1 * d1 + d2 * d2) * inv2t);
            }
            sum[k] = s;
        }
        // combine the 4 batch-quads (xor lane bits 0-1 within the node's 8)
#pragma unroll
        for (int k = 0; k < 8; ++k) {
            sum[k] += __shfl_xor(sum[k], 1, 8);
            sum[k] += __shfl_xor(sum[k], 2, 8);
        }
        float deg = 0.f, sw2 = 0.f;
        float wk2[2];
#pragma unroll
        for (int k = 0; k < 8; ++k) {
            float wk = sum[k] * (1.f / BB) * ((idx[k] >= 0) ? 1.f : 0.f);
            deg += wk;
            sw2 += wk * wk;
            if ((k >> 1) == bq) wk2[k & 1] = wk;
        }
        *(float2*)(wl + (size_t)n * KK + h * 8 + bq * 2) =
            make_float2(wk2[0], wk2[1]);
        // merge the two khalves for deg / F-norm / maxdeg
        deg += __shfl_xor(deg, 4, 8);
        sw2 += __shfl_xor(sw2, 4, 8);
        tp = (lid == 0) ? (deg * deg + sw2) : 0.f;
        dm = (lid == 0) ? deg : 0.f;
    }
#pragma unroll
    for (int off = 32; off > 0; off >>= 1) {
        tp += __shfl_down(tp, off);
        dm = fmaxf(dm, __shfl_down(dm, off));
    }
    int lane = threadIdx.x & 63, wid = threadIdx.x >> 6;
    if (lane == 0) { ldsS[wid] = tp; ldsM[wid] = dm; }
    __syncthreads();
    if (threadIdx.x == 0) {
        float ss = 0.f, sm = 0.f;
        int nw = blockDim.x >> 6;
        for (int wv = 0; wv < nw; ++wv) {
            ss += ldsS[wv];
            sm = fmaxf(sm, ldsM[wv]);
        }
        atomicAdd(sc, ss);
        atomicMax((int*)sc + 2, __float_as_int(sm));
    }
}

// Two-term Chebyshev step k (thread = (node n, quad q)):
//   x_{k+1} = x_k + c1*(x_k - x_{k-1}) + c2*(b - A x_k)
// Centers and recurrence in f32; neighbor GATHERS from an f16 copy (Gh):
// 32B rows -> one 4-lane instruction per neighbor row. k==1 runs on Bt/Bth
// (x1 = b/theta folded via linearity); k==2 recomputes x_prev = bt/theta.
// k<NCHEB writes both f32 state and its f16 copy; k==NCHEB writes out.
__global__ void __launch_bounds__(256, 3)
k_cheb(const int* __restrict__ nl,
       const float* __restrict__ wl,
       const float* __restrict__ Xcur,   // f32 center: k==1 Bt, k==2 Xa
       const __half* __restrict__ Gh,    // f16 gather table: k==1 Bth, k==2 Xah
       const float* __restrict__ Bt,
       float* __restrict__ Xout,         // k==1: Xa
       __half* __restrict__ XoutH,       // k==1: Xah
       const float* __restrict__ sc,
       float* __restrict__ out,
       int N, int k) {
    int t = blockIdx.x * blockDim.x + threadIdx.x;
    if (t >= N * 4) return;
    int n = t >> 2, q = t & 3;
    float musc, theta, delta;
    cheb_params(sc, musc, theta, delta);
    float sig1 = theta / delta;
    float rp = delta / theta;              // rho_0
    float rk = rp;
    for (int j = 1; j <= k; ++j) {
        rk = 1.f / (2.f * sig1 - rp);
        if (j < k) rp = rk;
    }
    float c1 = rk * rp;
    float c2 = 2.f * rk / delta;
    float invt = 1.f / theta;

    size_t o = (size_t)n * 16 + q * 4;
    v4f ck = *(const v4f*)(Xcur + o);      // f32 center (bt if k==1)
    int idx[KK];
    float wr[KK];
#pragma unroll
    for (int qq = 0; qq < 4; ++qq) {
        int4 iv = ((const int4*)(nl + (size_t)n * KK))[qq];
        iv.x = iv.x < 0 ? 0 : iv.x;
        iv.y = iv.y < 0 ? 0 : iv.y;
        iv.z = iv.z < 0 ? 0 : iv.z;
        iv.w = iv.w < 0 ? 0 : iv.w;
        ((int4*)idx)[qq] = iv;
        ((float4*)wr)[qq] = ((const float4*)(wl + (size_t)n * KK))[qq];
    }
    uint2 gv[KK];
#pragma unroll
    for (int kk = 0; kk < KK; ++kk)
        gv[kk] = *(const uint2*)(Gh + (size_t)idx[kk] * 16 + q * 4);
    v4f acc = {0.f, 0.f, 0.f, 0.f};
#pragma unroll
    for (int kk = 0; kk < KK; ++kk) {
        const __half2* hp = (const __half2*)&gv[kk];
        float2 a = __half22float2(hp[0]);
        float2 b = __half22float2(hp[1]);
        v4f v = {a.x, a.y, b.x, b.y};
        acc += (ck - v) * wr[kk];
    }
    v4f axr = ck + acc * musc;             // A applied to raw rows

    v4f xn;
    if (k == 1) {
        // x2 = (invt*(1+c1)+c2)*b - c2*invt*(A b)
        v4f bt = ck;
        xn = bt * (invt * (1.f + c1) + c2) - axr * (c2 * invt);
    } else {
        v4f bt = *(const v4f*)(Bt + o);
        v4f xp = bt * invt;                // NCHEB==2: k==2 path only
        xn = ck + (ck - xp) * c1 + (bt - axr) * c2;
    }

    if (k == NCHEB) {
        out[(size_t)(q * 4 + 0) * N + n] = xn.x;
        out[(size_t)(q * 4 + 1) * N + n] = xn.y;
        out[(size_t)(q * 4 + 2) * N + n] = xn.z;
        out[(size_t)(q * 4 + 3) * N + n] = xn.w;
    } else {
        *(v4f*)(Xout + o) = xn;
        __half2 h0 = __floats2half2_rn(xn.x, xn.y);
        __half2 h1 = __floats2half2_rn(xn.z, xn.w);
        uint2 u;
        u.x = *(const unsigned*)&h0;
        u.y = *(const unsigned*)&h1;
        *(uint2*)(XoutH + o) = u;
    }
}

extern "C" void kernel_launch(void* const* d_in, const int* in_sizes, int n_in,
                              void* d_out, int out_size, void* d_ws, size_t ws_size,
                              hipStream_t stream) {
    const float* x   = (const float*)d_in[0];
    const int*   nl  = (const int*)d_in[1];
    const float* emb = (const float*)d_in[2];
    const float* fcw = (const float*)d_in[3];
    const float* fcb = (const float*)d_in[4];
    const float* th  = (const float*)d_in[5];
    int N = in_sizes[1] / KK;   // 50000

    // ws (floats, no aliasing; total ~80N+512 ≈ 16 MB of ~256 MB):
    //   sc[512] | wl[16N] | ffp8(16N f32-equiv) | Bt[16N] |
    //   Bth(f16, 8N f32-equiv) | Xa[16N] | Xah(f16, 8N f32-equiv)
    float* sc  = (float*)d_ws;
    float* wl  = sc + 512;
    unsigned char* ffp8 = (unsigned char*)(wl + (size_t)N * 16);
    float* Bt  = wl + (size_t)N * 32;
    __half* Bth = (__half*)(Bt + (size_t)N * 16);
    float* Xa  = Bt + (size_t)N * 24;
    __half* Xah = (__half*)(Xa + (size_t)N * 16);
    float* outp = (float*)d_out;

    int G1 = (N + 255) / 256;
    int G8 = (N * 8 + 255) / 256;
    int G4 = (N * 4 + 255) / 256;

    k_feat<<<G1, 256, 0, stream>>>(x, emb, fcw, fcb, ffp8, Bt, Bth, sc, N);
    k_weights<<<G8, 256, 0, stream>>>(nl, ffp8, th, wl, sc, N);
    // step 1: Bt/Bth -> Xa/Xah;  step 2: Xa/Xah (+Bt) -> out
    k_cheb<<<G4, 256, 0, stream>>>(nl, wl, Bt, Bth, Bt, Xa, Xah, sc, outp, N, 1);
    k_cheb<<<G4, 256, 0, stream>>>(nl, wl, Xa, Xah, Bt, nullptr, nullptr, sc, outp, N, 2);
}

// Round 24
// 58.338 us; speedup vs baseline: 1.3085x; 1.3085x over previous
//
#include <hip/hip_runtime.h>
#include <hip/hip_fp16.h>
#include <hip/hip_fp8.h>

#define MU_C     0.5f
#define C_NORM_C 8.0f
#define LRELU_C  0.2f
#define NCHEB    2   // output x_3; measured-kappa (~1.07) err ~6e-4 << 0.098

constexpr int BB = 16;   // batch
constexpr int KK = 16;   // neighbors
constexpr int EE = 6;    // embedding dim

typedef float v4f __attribute__((ext_vector_type(4)));

// ws scalar slots: sc[0] = norm accumulator (sum deg^2 + sum w^2)
//                  sc[2] = max_n deg_n (float bits via int atomicMax)

__device__ __forceinline__ void cheb_params(const float* __restrict__ sc,
                                            float& musc, float& theta, float& delta) {
    float scale = C_NORM_C * rsqrtf(sc[0] + 1e-30f);
    musc = MU_C * scale;
    float mdeg = __int_as_float(((const int*)sc)[2]) * scale;
    float lub = 1.f + MU_C * fminf(2.f * mdeg, 8.f);
    theta = 0.5f * (lub + 1.f);
    delta = fmaxf(0.5f * (lub - 1.f), 1e-12f);
}

// Features quantized to fp8 e4m3 (self-consistent pack/unpack; w
// perturbation under the bf16 output floor — measured r22).
// Row = 64B/node: byte = bq*16 + sub*4 + f  (b = bq*4+sub; f3 = pad).
// Also writes Bt = x^T f32 (N,16) and Bth = x^T f16 (N,16).
// Block 0 zeroes the scalar slots.
__global__ void k_feat(const float* __restrict__ x,
                       const float* __restrict__ emb,
                       const float* __restrict__ fcw,
                       const float* __restrict__ fcb,
                       unsigned char* __restrict__ ffp8,
                       float* __restrict__ Bt,
                       __half* __restrict__ Bth,
                       float* __restrict__ sc,
                       int N) {
    if (blockIdx.x == 0 && threadIdx.x < 64) sc[threadIdx.x] = 0.f;
    int n = blockIdx.x * blockDim.x + threadIdx.x;
    if (n >= N) return;
    float ev[EE];
#pragma unroll
    for (int j = 0; j < EE; ++j) ev[j] = emb[(size_t)n * EE + j];
    float g[3], w0[3];
#pragma unroll
    for (int f = 0; f < 3; ++f) {
        w0[f] = fcw[f * (EE + 1)];
        float s = fcb[f];
#pragma unroll
        for (int j = 0; j < EE; ++j) s += fcw[f * (EE + 1) + 1 + j] * ev[j];
        g[f] = s;
    }
    unsigned char hb8[64];
    float bt[BB];
    __half bth[BB];
#pragma unroll
    for (int b = 0; b < BB; ++b) {
        float xv = x[(size_t)b * N + n];
        bt[b] = xv;
        bth[b] = __float2half(xv);
        int bq = b >> 2, sub = b & 3;
        int base = bq * 16 + sub * 4;
#pragma unroll
        for (int f = 0; f < 3; ++f) {
            float v = g[f] + w0[f] * xv;
            v = (v >= 0.f) ? v : LRELU_C * v;
            __hip_fp8_e4m3 q(v);
            hb8[base + f] = (unsigned char)q.__x;
        }
        hb8[base + 3] = 0;
    }
    uint4* dst = (uint4*)(ffp8 + (size_t)n * 64);
#pragma unroll
    for (int q = 0; q < 4; ++q) dst[q] = ((const uint4*)hb8)[q];
    float4* db = (float4*)(Bt + (size_t)n * 16);
#pragma unroll
    for (int q = 0; q < 4; ++q) db[q] = ((const float4*)bt)[q];
    uint4* dh = (uint4*)(Bth + (size_t)n * 16);
#pragma unroll
    for (int q = 0; q < 2; ++q) dh[q] = ((const uint4*)bth)[q];
}

__device__ __forceinline__ void unpack_fp8_12(uint4 u, float* f) {
    const unsigned char* b = (const unsigned char*)&u;
#pragma unroll
    for (int sub = 0; sub < 4; ++sub) {
#pragma unroll
        for (int ff = 0; ff < 3; ++ff) {
            __hip_fp8_e4m3 h;
            h.__x = (__hip_fp8_storage_t)b[sub * 4 + ff];
            f[sub * 4 + ff] = (float)h;
        }
    }
}

// Similarity weights — measured-best shape (4 lanes/node, adjacent; 16
// neighbors per lane; ONE uint4 load per lane per neighbor on fp8 rows).
// Five structural alternatives (r11/r15/r20/r23 grid/lane splits) all
// regressed ~2x; this decomposition is the empirical optimum.
__global__ void __launch_bounds__(256, 2)
k_weights(const int* __restrict__ nl,
          const unsigned char* __restrict__ ffp8,
          const float* __restrict__ theta_p,
          float* __restrict__ wl,
          float* __restrict__ sc,
          int N) {
    __shared__ float ldsS[8];
    __shared__ float ldsM[8];
    int t = blockIdx.x * blockDim.x + threadIdx.x;
    int n = t >> 2, bq = t & 3;
    float tp = 0.f, dm = 0.f;
    if (n < N) {
        float inv2t = 0.5f / theta_p[0];
        const uint4* fu = (const uint4*)ffp8;     // 4 uint4 per node row
        uint4 su = fu[(size_t)n * 4 + bq];
        float fs[16];
        unpack_fp8_12(su, fs);
        int idx[KK];
#pragma unroll
        for (int q = 0; q < 4; ++q)
            ((int4*)idx)[q] = ((const int4*)(nl + (size_t)n * KK))[q];
        float sum[KK];
#pragma unroll
        for (int k = 0; k < KK; ++k) {
            int nbs = idx[k] < 0 ? 0 : idx[k];
            uint4 nu = fu[(size_t)nbs * 4 + bq];
            float fn[16];
            unpack_fp8_12(nu, fn);
            float s = 0.f;
#pragma unroll
            for (int b = 0; b < 4; ++b) {
                float d0 = fs[b * 4 + 0] - fn[b * 4 + 0];
                float d1 = fs[b * 4 + 1] - fn[b * 4 + 1];
                float d2 = fs[b * 4 + 2] - fn[b * 4 + 2];
                s += __expf(-(d0 * d0 + d1 * d1 + d2 * d2) * inv2t);
            }
            sum[k] = s;
        }
        // combine the 4 batch-quads (adjacent lanes of one node)
#pragma unroll
        for (int k = 0; k < KK; ++k) {
            sum[k] += __shfl_xor(sum[k], 1, 4);
            sum[k] += __shfl_xor(sum[k], 2, 4);
        }
        float deg = 0.f, sw2 = 0.f;
        float wk4[4];
#pragma unroll
        for (int k = 0; k < KK; ++k) {
            float wk = sum[k] * (1.f / BB) * ((idx[k] >= 0) ? 1.f : 0.f);
            deg += wk;
            sw2 += wk * wk;
            if ((k >> 2) == bq) wk4[k & 3] = wk;
        }
        *(float4*)(wl + (size_t)n * KK + bq * 4) =
            make_float4(wk4[0], wk4[1], wk4[2], wk4[3]);
        tp = (bq == 0) ? (deg * deg + sw2) : 0.f;
        dm = (bq == 0) ? deg : 0.f;
    }
#pragma unroll
    for (int off = 32; off > 0; off >>= 1) {
        tp += __shfl_down(tp, off);
        dm = fmaxf(dm, __shfl_down(dm, off));
    }
    int lane = threadIdx.x & 63, wid = threadIdx.x >> 6;
    if (lane == 0) { ldsS[wid] = tp; ldsM[wid] = dm; }
    __syncthreads();
    if (threadIdx.x == 0) {
        float ss = 0.f, sm = 0.f;
        int nw = blockDim.x >> 6;
        for (int wv = 0; wv < nw; ++wv) {
            ss += ldsS[wv];
            sm = fmaxf(sm, ldsM[wv]);
        }
        atomicAdd(sc, ss);
        atomicMax((int*)sc + 2, __float_as_int(sm));
    }
}

// Two-term Chebyshev step k (thread = (node n, quad q)):
//   x_{k+1} = x_k + c1*(x_k - x_{k-1}) + c2*(b - A x_k)
// Recurrence in f32; x-state lives ONLY as an f16 table (Gh): cheb1 reads
// f32 Bt centers + f16 Bth gathers and writes x2 to Xah (f16 only);
// cheb2 reads BOTH center and gathers from Xah (center-in-f16 error
// ~(1+c1+c2)*eps_f16*|x2| ~ 2.5e-3 << 0.0156 floor), x_prev = bt/theta.
__global__ void __launch_bounds__(256, 3)
k_cheb(const int* __restrict__ nl,
       const float* __restrict__ wl,
       const float* __restrict__ Xcur,   // k==1: Bt (f32); k==2: unused
       const __half* __restrict__ Gh,    // f16 table: k==1 Bth, k==2 Xah
       const float* __restrict__ Bt,
       __half* __restrict__ XoutH,       // k==1: Xah
       const float* __restrict__ sc,
       float* __restrict__ out,
       int N, int k) {
    int t = blockIdx.x * blockDim.x + threadIdx.x;
    if (t >= N * 4) return;
    int n = t >> 2, q = t & 3;
    float musc, theta, delta;
    cheb_params(sc, musc, theta, delta);
    float sig1 = theta / delta;
    float rp = delta / theta;              // rho_0
    float rk = rp;
    for (int j = 1; j <= k; ++j) {
        rk = 1.f / (2.f * sig1 - rp);
        if (j < k) rp = rk;
    }
    float c1 = rk * rp;
    float c2 = 2.f * rk / delta;
    float invt = 1.f / theta;

    size_t o = (size_t)n * 16 + q * 4;
    v4f ck;
    if (k == 1) {
        ck = *(const v4f*)(Xcur + o);      // f32 b row
    } else {
        uint2 cu = *(const uint2*)(Gh + o);
        const __half2* hp = (const __half2*)&cu;
        float2 a = __half22float2(hp[0]);
        float2 b = __half22float2(hp[1]);
        ck = (v4f){a.x, a.y, b.x, b.y};    // f16 x2 row
    }
    int idx[KK];
    float wr[KK];
#pragma unroll
    for (int qq = 0; qq < 4; ++qq) {
        int4 iv = ((const int4*)(nl + (size_t)n * KK))[qq];
        iv.x = iv.x < 0 ? 0 : iv.x;
        iv.y = iv.y < 0 ? 0 : iv.y;
        iv.z = iv.z < 0 ? 0 : iv.z;
        iv.w = iv.w < 0 ? 0 : iv.w;
        ((int4*)idx)[qq] = iv;
        ((float4*)wr)[qq] = ((const float4*)(wl + (size_t)n * KK))[qq];
    }
    uint2 gv[KK];
#pragma unroll
    for (int kk = 0; kk < KK; ++kk)
        gv[kk] = *(const uint2*)(Gh + (size_t)idx[kk] * 16 + q * 4);
    v4f acc = {0.f, 0.f, 0.f, 0.f};
#pragma unroll
    for (int kk = 0; kk < KK; ++kk) {
        const __half2* hp = (const __half2*)&gv[kk];
        float2 a = __half22float2(hp[0]);
        float2 b = __half22float2(hp[1]);
        v4f v = {a.x, a.y, b.x, b.y};
        acc += (ck - v) * wr[kk];
    }
    v4f axr = ck + acc * musc;             // A applied to raw rows

    v4f xn;
    if (k == 1) {
        // x2 = (invt*(1+c1)+c2)*b - c2*invt*(A b)
        v4f bt = ck;
        xn = bt * (invt * (1.f + c1) + c2) - axr * (c2 * invt);
    } else {
        v4f bt = *(const v4f*)(Bt + o);
        v4f xp = bt * invt;                // NCHEB==2: k==2 path only
        xn = ck + (ck - xp) * c1 + (bt - axr) * c2;
    }

    if (k == NCHEB) {
        out[(size_t)(q * 4 + 0) * N + n] = xn.x;
        out[(size_t)(q * 4 + 1) * N + n] = xn.y;
        out[(size_t)(q * 4 + 2) * N + n] = xn.z;
        out[(size_t)(q * 4 + 3) * N + n] = xn.w;
    } else {
        __half2 h0 = __floats2half2_rn(xn.x, xn.y);
        __half2 h1 = __floats2half2_rn(xn.z, xn.w);
        uint2 u;
        u.x = *(const unsigned*)&h0;
        u.y = *(const unsigned*)&h1;
        *(uint2*)(XoutH + o) = u;
    }
}

extern "C" void kernel_launch(void* const* d_in, const int* in_sizes, int n_in,
                              void* d_out, int out_size, void* d_ws, size_t ws_size,
                              hipStream_t stream) {
    const float* x   = (const float*)d_in[0];
    const int*   nl  = (const int*)d_in[1];
    const float* emb = (const float*)d_in[2];
    const float* fcw = (const float*)d_in[3];
    const float* fcb = (const float*)d_in[4];
    const float* th  = (const float*)d_in[5];
    int N = in_sizes[1] / KK;   // 50000

    // ws (floats, no aliasing):
    //   sc[512] | wl[16N] | ffp8(16N f32-equiv) | Bt[16N] |
    //   Bth(f16, 8N f32-equiv) | Xah(f16, 8N f32-equiv)
    float* sc  = (float*)d_ws;
    float* wl  = sc + 512;
    unsigned char* ffp8 = (unsigned char*)(wl + (size_t)N * 16);
    float* Bt  = wl + (size_t)N * 32;
    __half* Bth = (__half*)(Bt + (size_t)N * 16);
    __half* Xah = (__half*)(Bt + (size_t)N * 24);
    float* outp = (float*)d_out;

    int G1 = (N + 255) / 256;
    int G4 = (N * 4 + 255) / 256;

    k_feat<<<G1, 256, 0, stream>>>(x, emb, fcw, fcb, ffp8, Bt, Bth, sc, N);
    k_weights<<<G4, 256, 0, stream>>>(nl, ffp8, th, wl, sc, N);
    // step 1: Bt/Bth -> Xah;  step 2: Xah (+Bt) -> out
    k_cheb<<<G4, 256, 0, stream>>>(nl, wl, Bt, Bth, Bt, Xah, sc, outp, N, 1);
    k_cheb<<<G4, 256, 0, stream>>>(nl, wl, nullptr, Xah, Bt, nullptr, sc, outp, N, 2);
}